// Round 6
// baseline (38773.615 us; speedup 1.0000x reference)
//
#include <hip/hip_runtime.h>
#include <stdint.h>
#include <math.h>

// pred_out [8,5,768,768] f32, target_mask [8,1,768,768] i32 (0..3), num_target_classes=4.
#define B_ 8
#define C_ 5
#define H_ 768
#define W_ 768
#define HW_ (H_*W_)
#define HWq (HW_/4)            // 147456 float4 per plane
#define NPIX (B_*HW_)          // 4,718,592
#define TB 8
#define INVAL 0xFFFFFFFFu
#define LN2F 0.69314718056f
#define BIASF 16.2f
#define TILE 32
#define TPR 24                 // tiles per row (W/32)
#define TPC 24                 // tile rows (H/32)
#define NTILES (B_*TPR*TPC)    // 4608
#define NPT 128                // border nodes per tile (4*32)
#define NNODES (NTILES*NPT)    // 589,824
#define NCOPY 16               // histogram replicas
#define EPI (23*24*2)          // edges per image: 552 vertical + 552 horizontal
#define NEDGE (B_*EPI)         // 8832
// zero region: ctrl(16 u32) + spf(160 f64 = 320 u32) + flags(8832 u32)
#define ZWORDS (16 + 320 + NEDGE)   // 9168
#define ZBLK 36

typedef unsigned long long ull;

// ---------------- compact node union-find (lock-free, agent scope, coherent-point) ---------
static __device__ __forceinline__ unsigned pload(const unsigned* P, unsigned i) {
  return __hip_atomic_load(&P[i], __ATOMIC_RELAXED, __HIP_MEMORY_SCOPE_AGENT);
}
static __device__ unsigned findRootG(unsigned* P, unsigned i) {
  unsigned p = pload(P, i);
  if (p == i) return i;
  unsigned gp = pload(P, p);
  while (p != gp) {
    __hip_atomic_store(&P[i], gp, __ATOMIC_RELAXED, __HIP_MEMORY_SCOPE_AGENT);  // path halving
    i = p; p = gp; gp = pload(P, p);
  }
  return p;
}
static __device__ bool uniteG(unsigned* P, unsigned a, unsigned b) {
  a = findRootG(P, a);
  b = findRootG(P, b);
  while (a != b) {
    if (a < b) { unsigned t = a; a = b; b = t; }
    unsigned old = atomicCAS(&P[a], a, b);
    if (old == a) return true;     // one real merge
    a = findRootG(P, old);
    b = findRootG(P, b);
  }
  return false;
}
// ---------------- LDS union-find with high-16-bit payload (workgroup scope) ----------------
static __device__ __forceinline__ unsigned ploadL(const unsigned* P, unsigned i) {
  return __hip_atomic_load(&P[i], __ATOMIC_RELAXED, __HIP_MEMORY_SCOPE_WORKGROUP);
}
static __device__ unsigned findRootL(const unsigned* P, unsigned i) {
  unsigned p = ploadL(P, i) & 0xFFFFu;
  while (p != i) { i = p; p = ploadL(P, i) & 0xFFFFu; }
  return i;
}
static __device__ void uniteL(unsigned* P, unsigned a, unsigned b) {
  a = findRootL(P, a);
  b = findRootL(P, b);
  while (a != b) {
    if (a < b) { unsigned t = a; a = b; b = t; }
    unsigned old = atomicCAS(&P[a], 0xFFFF0000u | a, 0xFFFF0000u | b);
    if (old == (0xFFFF0000u | a)) return;
    a = findRootL(P, old & 0xFFFFu);
    b = findRootL(P, b);
  }
}
// exact f64 accumulation via CAS (values are dyadic rationals -> order-independent, bit-exact)
static __device__ void casAddD(double* p, double v) {
  ull* up = (ull*)p;
  ull old = __hip_atomic_load(up, __ATOMIC_RELAXED, __HIP_MEMORY_SCOPE_AGENT);
  for (;;) {
    double nv = __longlong_as_double((long long)old) + v;
    ull nvu = (ull)__double_as_longlong(nv);
    if (__hip_atomic_compare_exchange_strong(up, &old, nvu,
          __ATOMIC_RELAXED, __ATOMIC_RELAXED, __HIP_MEMORY_SCOPE_AGENT)) break;
  }
}

// ---------------- k0: zero control region (ctrl | spf | flags), workspace is poisoned ------
__global__ __launch_bounds__(256) void k_zero(unsigned* __restrict__ z) {
  unsigned idx = blockIdx.x * 256u + threadIdx.x;
  if (idx < ZWORDS) z[idx] = 0u;
}

// ---------------- k_fused: stats + tile-CCL + seam-arbitration + last-block finalize -------
// hist word: [63:57] cnt | [56:38] sum pred*2^12 | [37:20] sum (logit+16.2)*2^6 | [16:0] sum mag*2^6
#define SH_CNT(t,c)   shist[((t)*C_+(c))*4 + 0]
#define SH_PRED(t,c)  shist[((t)*C_+(c))*4 + 1]
#define SH_LRAW(t,c)  shist[((t)*C_+(c))*4 + 2]
#define SH_MAG(t,c)   shist[((t)*C_+(c))*4 + 3]
__global__ __launch_bounds__(256, 8) void k_fused(
    const float* __restrict__ pred, const int* __restrict__ tgt,
    const int* __restrict__ ntcp,
    unsigned* __restrict__ border32, unsigned* __restrict__ P2,
    unsigned* __restrict__ flags, unsigned* __restrict__ ctrl,
    double* __restrict__ spf, float* __restrict__ out)
{
  __shared__ ull h[NCOPY][41];               // 5,248 B
  __shared__ unsigned lab[TILE*TILE];        // 4 KB (payload in high 16 bits)
  __shared__ unsigned lclsw[TILE*TILE/4];    // 1 KB
  __shared__ unsigned s_rt[4], s_sm[4];
  __shared__ unsigned s_bord[NPT];
  __shared__ int s_win[4];
  __shared__ int s_last;
  // finalize-phase arrays (used only by the last block)
  __shared__ double shist[160];
  __shared__ double s_col[C_][3];
  __shared__ unsigned s_cnti[TB*C_];
  __shared__ unsigned s_ctot[C_];
  __shared__ unsigned s_nc[4], s_smg[4];
  __shared__ float s_ph[C_];
  __shared__ double s_term[TB];
  __shared__ int s_NT;
  __shared__ int s_nun;
  unsigned char* lcls = (unsigned char*)lclsw;

  for (int i = threadIdx.x; i < NCOPY*41; i += 256) (&h[0][0])[i] = 0ull;
  if (threadIdx.x < 4) { s_rt[threadIdx.x] = 0u; s_sm[threadIdx.x] = 0u; }
  if (threadIdx.x < NPT) {   // agent-scope init: bypasses local L2 (readable cross-XCD)
    unsigned n = (unsigned)blockIdx.x * NPT + threadIdx.x;
    __hip_atomic_store(&P2[n], n, __ATOMIC_RELAXED, __HIP_MEMORY_SCOPE_AGENT);
  }
  __syncthreads();

  const int cp = threadIdx.x & (NCOPY - 1);
  int blk = blockIdx.x;
  int b = blk / (TPR*TPC);
  int rem = blk - b * (TPR*TPC);
  int trow = rem / TPR;
  int tcol = rem - trow * TPR;
  int ty0 = trow * TILE;
  int tx0 = tcol * TILE;

  // ---- load + stats phase: one quad per thread ----
  unsigned pk = 0u;
  {
    const int baseq = ty0 * (W_/4) + (tx0 >> 2);
    const int qrow = threadIdx.x >> 3, qcol = threadIdx.x & 7;
    const int o = qrow * (W_/4) + qcol;
    const float4* pp = (const float4*)pred + (size_t)b * (C_*HWq) + baseq + o;
    float4 a0 = pp[0];
    float4 a1 = pp[HWq];
    float4 a2 = pp[2*HWq];
    float4 a3 = pp[3*HWq];
    float4 a4 = pp[4*HWq];
    int4 t4 = ((const int4*)tgt)[(size_t)b * HWq + baseq + o];
#pragma unroll
    for (int j = 0; j < 4; ++j) {
      float v0 = ((const float*)&a0)[j];
      float v1 = ((const float*)&a1)[j];
      float v2 = ((const float*)&a2)[j];
      float v3 = ((const float*)&a3)[j];
      float v4 = ((const float*)&a4)[j];
      int tt = ((const int*)&t4)[j];
      float best = v0; int bc = 0;
      if (v1 > best) { best = v1; bc = 1; }
      if (v2 > best) { best = v2; bc = 2; }
      if (v3 > best) { best = v3; bc = 3; }
      if (v4 > best) { best = v4; bc = 4; }
      unsigned tu = (unsigned)tt; if (tu >= TB) tu = TB - 1;
      ull w;
      if (bc) {
        float pc = fminf(fmaxf(best, 1e-7f), 1.0f - 1e-7f);
        float l2p = __log2f(pc);
        float l2m = __log2f(1.0f - pc);
        float logit = (l2p - l2m) * LN2F;
        float mag   = -l2m * LN2F;
        w = (1ull << 57)
          | ((ull)__float2uint_rn(best * 4096.0f) << 38)
          | ((ull)__float2uint_rn((logit + BIASF) * 64.0f) << 20)
          | (ull)__float2uint_rn(mag * 64.0f);
      } else {
        w = 1ull << 57;
      }
      atomicAdd(&h[cp][(int)tu * C_ + bc], w);
      pk |= ((unsigned)bc) << (8 * j);
    }
    lclsw[threadIdx.x] = pk;
  }
  __syncthreads();

  // ---- CCL phase: thread owns its own 4-px quad ----
  const int r = threadIdx.x >> 3, sub = threadIdx.x & 7;
  const int seg = r * TILE + sub * 4;
  unsigned Dw = (r < TILE-1) ? lclsw[threadIdx.x + 8] : 0u;
  unsigned rb = (sub < 7) ? (lclsw[threadIdx.x + 1] & 255u) : 0u;
  {
    uint4 lw;
    unsigned* lp = (unsigned*)&lw;
#pragma unroll
    for (int k = 0; k < 4; ++k) {
      int li = seg + k;
      unsigned c = (pk >> (8 * k)) & 255u;
      lp[k] = c ? (0xFFFF0000u | (unsigned)li) : INVAL;
    }
    *(uint4*)&lab[seg] = lw;
  }
  __syncthreads();

#pragma unroll
  for (int j = 0; j < 4; ++j) {
    unsigned c = (pk >> (8 * j)) & 255u;
    if (!c) continue;
    int li = seg + j;
    unsigned cr = (j < 3) ? ((pk >> (8 * (j + 1))) & 255u) : rb;
    if (cr == c) uniteL(lab, li, li + 1);
    if (((Dw >> (8 * j)) & 255u) == c) uniteL(lab, li, li + TILE);
  }
  __syncthreads();

  {
    uint4 lw = *(const uint4*)&lab[seg];
    const unsigned* lp = (const unsigned*)&lw;
#pragma unroll
    for (int k = 0; k < 4; ++k) {
      int li = seg + k;
      unsigned c = (pk >> (8 * k)) & 255u;
      if (c && (lp[k] & 0xFFFFu) == (unsigned)li) atomicAdd(&s_rt[c - 1], 1u);
    }
  }
  // border representative election (low 16 bits of lab[root] invariant under atomicMin)
  unsigned bc_c = 0, bc_rt = 0;
  if (threadIdx.x < NPT) {
    int bp = threadIdx.x;
    int tx, ty;
    if (bp < 32)       { ty = 0;       tx = bp; }
    else if (bp < 64)  { ty = TILE-1;  tx = bp - 32; }
    else if (bp < 96)  { tx = 0;       ty = bp - 64; }
    else               { tx = TILE-1;  ty = bp - 96; }
    int li = ty * TILE + tx;
    bc_c = lcls[li];
    if (bc_c) {
      bc_rt = findRootL(lab, (unsigned)li);
      atomicMin(&lab[bc_rt], ((unsigned)threadIdx.x << 16) | bc_rt);
    }
  }
  __syncthreads();
  if (threadIdx.x < NPT) {
    unsigned sub2 = bc_c ? (lab[bc_rt] >> 16) : 0u;
    s_bord[threadIdx.x] = (bc_c << 8) | sub2;
  }
  __syncthreads();
  // publish border via agent-scope atomic stores (coherent point; no cross-XCD staleness)
  if (threadIdx.x < NPT/2) {
    unsigned wv = s_bord[2*threadIdx.x] | (s_bord[2*threadIdx.x + 1] << 16);
    __hip_atomic_store(&border32[blk * (NPT/2) + threadIdx.x], wv,
                       __ATOMIC_RELAXED, __HIP_MEMORY_SCOPE_AGENT);
  }
  __syncthreads();   // vmcnt drain: publish + P2 init globally visible before arbitration

  // ---- seam arbitration: second arriver on each edge owns it ----
  if (threadIdx.x < 4) {
    s_win[threadIdx.x] = 0;
    int valid = 0; unsigned eid = 0;
    if (threadIdx.x == 0) { valid = (trow > 0);       eid = b*EPI + (trow-1)*24 + tcol; }
    if (threadIdx.x == 1) { valid = (trow < TPC-1);   eid = b*EPI + trow*24 + tcol; }
    if (threadIdx.x == 2) { valid = (tcol > 0);       eid = b*EPI + 552 + trow*23 + (tcol-1); }
    if (threadIdx.x == 3) { valid = (tcol < TPR-1);   eid = b*EPI + 552 + trow*23 + tcol; }
    if (valid) {
      unsigned old = __hip_atomic_fetch_add(&flags[eid], 1u,
                       __ATOMIC_RELAXED, __HIP_MEMORY_SCOPE_AGENT);
      if (old == 1u) s_win[threadIdx.x] = 1;
    }
  }
  __syncthreads();
  {
    int d = threadIdx.x >> 5;
    int k = threadIdx.x & 31;
    if (d < 4 && s_win[d]) {
      int tA, tB, pA, pB;
      if (d == 0)      { tA = blk - TPR; tB = blk;       pA = 32 + k; pB = 0 + k; }
      else if (d == 1) { tA = blk;       tB = blk + TPR; pA = 32 + k; pB = 0 + k; }
      else if (d == 2) { tA = blk - 1;   tB = blk;       pA = 96 + k; pB = 64 + k; }
      else             { tA = blk;       tB = blk + 1;   pA = 96 + k; pB = 64 + k; }
      unsigned wA = __hip_atomic_load(&border32[tA * (NPT/2) + (pA >> 1)],
                      __ATOMIC_RELAXED, __HIP_MEMORY_SCOPE_AGENT);
      unsigned wB = __hip_atomic_load(&border32[tB * (NPT/2) + (pB >> 1)],
                      __ATOMIC_RELAXED, __HIP_MEMORY_SCOPE_AGENT);
      unsigned eA = (pA & 1) ? (wA >> 16) : (wA & 0xFFFFu);
      unsigned eB = (pB & 1) ? (wB >> 16) : (wB & 0xFFFFu);
      unsigned ca = eA >> 8, cb = eB >> 8;
      if (ca && ca == cb) {
        if (uniteG(P2, (unsigned)tA * NPT + (eA & 255u),
                       (unsigned)tB * NPT + (eB & 255u)))
          atomicAdd(&s_sm[ca - 1], 1u);
      }
    }
  }
  // ---- histogram fold -> exact global f64 accumulation ----
  if (threadIdx.x < 160) {
    int slot = threadIdx.x >> 2, comp = threadIdx.x & 3;
    double s = 0.0;
#pragma unroll
    for (int cc = 0; cc < NCOPY; ++cc) {
      ull w = h[cc][slot];
      if (comp == 0)      s += (double)(w >> 57);
      else if (comp == 1) s += (double)((w >> 38) & 0x7FFFFull) * (1.0/4096.0);
      else if (comp == 2) s += (double)((w >> 20) & 0x3FFFFull) * (1.0/64.0);
      else                s += (double)(w & 0x1FFFFull) * (1.0/64.0);
    }
    if (s != 0.0) casAddD(&spf[threadIdx.x], s);
  }
  __syncthreads();
  if (threadIdx.x < 4) {
    if (s_rt[threadIdx.x])
      __hip_atomic_fetch_add(&ctrl[threadIdx.x], s_rt[threadIdx.x],
                             __ATOMIC_RELAXED, __HIP_MEMORY_SCOPE_AGENT);
    if (s_sm[threadIdx.x])
      __hip_atomic_fetch_add(&ctrl[4 + threadIdx.x], s_sm[threadIdx.x],
                             __ATOMIC_RELAXED, __HIP_MEMORY_SCOPE_AGENT);
  }
  __syncthreads();   // all of this block's global atomics complete
  if (threadIdx.x == 0) {
    unsigned old = __hip_atomic_fetch_add(&ctrl[8], 1u,
                     __ATOMIC_RELAXED, __HIP_MEMORY_SCOPE_AGENT);
    s_last = (old == (unsigned)(NTILES - 1));
  }
  __syncthreads();
  if (!s_last) return;

  // ================= finalize (exactly one block reaches here) =================
  if (threadIdx.x < 160) {
    ull u = __hip_atomic_load((ull*)&spf[threadIdx.x],
              __ATOMIC_RELAXED, __HIP_MEMORY_SCOPE_AGENT);
    shist[threadIdx.x] = __longlong_as_double((long long)u);
  }
  if (threadIdx.x < 4) {
    s_nc[threadIdx.x]  = __hip_atomic_load(&ctrl[threadIdx.x],
                           __ATOMIC_RELAXED, __HIP_MEMORY_SCOPE_AGENT);
    s_smg[threadIdx.x] = __hip_atomic_load(&ctrl[4 + threadIdx.x],
                           __ATOMIC_RELAXED, __HIP_MEMORY_SCOPE_AGENT);
  }
  if (threadIdx.x < TB) s_term[threadIdx.x] = 0.0;
  if (threadIdx.x == 0) {
    int NT = ntcp[0];
    if (NT < 1) NT = 1;
    if (NT > TB) NT = TB;
    s_NT = NT;
  }
  __syncthreads();

  if (threadIdx.x < TB * C_) s_cnti[threadIdx.x] = (unsigned)llrint(shist[threadIdx.x * 4]);
  __syncthreads();

  if (threadIdx.x < C_) {
    int c = threadIdx.x;
    double sc = 0.0, sp2 = 0.0, sl = 0.0;
    unsigned ct = 0;
#pragma unroll
    for (int t = 0; t < TB; ++t) {
      sc += SH_CNT(t, c);
      sp2 += SH_PRED(t, c);
      sl += -SH_MAG(t, c);
      ct += s_cnti[t * C_ + c];
    }
    s_col[c][0] = sc; s_col[c][1] = sp2; s_col[c][2] = sl;
    s_ctot[c] = ct;
  }
  __syncthreads();

  // ph_tab: exact f32 replay incl. int32 wrap of n_comp*last_i
  if (threadIdx.x == 0) {
#pragma unroll
    for (int cc = 0; cc < C_; ++cc) {
      float ph = 0.0f;
      int li = 1;
#pragma unroll
      for (int v = 1; v < C_; ++v) {
        unsigned ncv = s_nc[v - 1] - s_smg[v - 1];
        if (s_ctot[v] > 0) {
          int prod = (int)(ncv * (unsigned)li);
          float sv = (float)prod;
          float inc = ((cc == v) ? 1.0f : 0.0f) + sv;
          ph = ph + inc;
          li = li + (int)ncv + ((s_ctot[v] < (unsigned)NPIX) ? 1 : 0);
        }
      }
      s_ph[cc] = ph;
    }
  }
  __syncthreads();

  const float EPSF = 1e-7f;
  const double L1 = (double)logf(1.0f - EPSF);
  const double M1 = (double)log1pf(-(1.0f - EPSF));
  const double L0 = (double)logf(EPSF);
  const double M0 = (double)log1pf(-EPSF);
  const double N = (double)NPIX;
  const double BIASD = (double)BIASF;
  const int NT = s_NT;

  if (threadIdx.x == 0) {
    double nt0 = 0;
#pragma unroll
    for (int c = 0; c < C_; ++c) nt0 += SH_CNT(0, c);
    double np1 = (double)s_ctot[0];
    double n11 = SH_CNT(0, 0);
    s_term[0] = -(n11*L1 + (nt0 - n11)*L0 + (np1 - n11)*M1 + (N - nt0 - np1 + n11)*M0) / N
                + 1.0 - (2.0*n11 + 1.0) / (np1 + nt0 + 1.0);
    int nun = 0;
    for (int t = 0; t < NT; ++t) {
      long long s = 0;
#pragma unroll
      for (int c = 0; c < C_; ++c) s += (long long)s_cnti[t * C_ + c];
      if (s) nun++;
    }
    s_nun = nun;
  } else if (threadIdx.x < (unsigned)NT) {
    int t = threadIdx.x;
    long long ntti = 0;
#pragma unroll
    for (int c = 0; c < C_; ++c) ntti += (long long)s_cnti[t * C_ + c];
    if (ntti != 0) {
      double ntt = 0;
#pragma unroll
      for (int c = 0; c < C_; ++c) ntt += SH_CNT(t, c);
      float pht[C_] = {s_ph[0], s_ph[1], s_ph[2], s_ph[3], s_ph[4]};
      int idx[C_] = {0, 1, 2, 3, 4};
#pragma unroll
      for (int i = 1; i < C_; ++i)
        for (int j = i; j > 0 && pht[idx[j]] < pht[idx[j-1]]; --j) {
          int tmp = idx[j]; idx[j] = idx[j-1]; idx[j-1] = tmp;
        }
      long long k = (ntti - 1) / 2;
      float med = pht[idx[C_ - 1]];
      long long cum = 0;
#pragma unroll
      for (int i = 0; i < C_; ++i) {
        cum += (long long)s_cnti[t * C_ + idx[i]];
        if (cum > k) { med = pht[idx[i]]; break; }
      }
      double A = 0, Bt = 0, inter = 0, sum_p = 0, ex = 0, nfg_t = 0, nfg_all = 0;
#pragma unroll
      for (int c = 1; c < C_; ++c) {
        double cnt_tc = SH_CNT(t, c);
        double mag_tc = SH_MAG(t, c);
        double spred_tc = SH_PRED(t, c);
        if (pht[c] == med) {
          double logit = SH_LRAW(t, c) - BIASD * cnt_tc;
          A += logit - mag_tc;                 // logpc = logit + log1m
          inter += spred_tc;
          nfg_t += cnt_tc;
          nfg_all += s_col[c][0];
          sum_p += s_col[c][1];
          Bt += s_col[c][2] - (-mag_tc);       // sum over t2 != t of log1m
        } else {
          ex += spred_tc;
        }
      }
      double bce  = -(A + Bt + (ntt - nfg_t)*L0 + (N - ntt - (nfg_all - nfg_t))*M0) / N;
      double dice = 1.0 - (2.0*inter + 1.0) / (sum_p + ntt + 1.0);
      s_term[t] = bce + dice + ex / ntt;
    }
  }
  __syncthreads();
  if (threadIdx.x == 0) {
    double res = 0.0;
#pragma unroll
    for (int t = 0; t < TB; ++t) res += s_term[t];
    out[0] = (float)(res / (double)(2 * s_nun + 1));
  }
}

extern "C" void kernel_launch(void* const* d_in, const int* in_sizes, int n_in,
                              void* d_out, int out_size, void* d_ws, size_t ws_size,
                              hipStream_t stream) {
  const float* pred = (const float*)d_in[0];
  const int* tgt = (const int*)d_in[1];
  const int* ntc = (const int*)d_in[2];
  float* out = (float*)d_out;
  char* ws = (char*)d_ws;
  // ws layout: ctrl(16 u32) | spf(160 f64) | flags(8832 u32) | P2 | border32  (~3.6 MB)
  size_t off = 0;
  unsigned* ctrl = (unsigned*)(ws + off);        off += 16 * 4;                     // 64
  double* spf = (double*)(ws + off);             off += 160 * 8;                    // 1,280
  unsigned* flags = (unsigned*)(ws + off);       off += (size_t)NEDGE * 4;          // 35,328
  unsigned* P2 = (unsigned*)(ws + off);          off += (size_t)NNODES * 4;         // 2,359,296
  unsigned* border32 = (unsigned*)(ws + off);    off += (size_t)NTILES * (NPT/2) * 4; // 1,179,648

  hipLaunchKernelGGL(k_zero, dim3(ZBLK), dim3(256), 0, stream, (unsigned*)ws);
  hipLaunchKernelGGL(k_fused, dim3(NTILES), dim3(256), 0, stream,
                     pred, tgt, ntc, border32, P2, flags, ctrl, spf, out);
}

// Round 7
// 198.524 us; speedup vs baseline: 195.3099x; 195.3099x over previous
//
#include <hip/hip_runtime.h>
#include <stdint.h>
#include <math.h>

// pred_out [8,5,768,768] f32, target_mask [8,1,768,768] i32 (0..3), num_target_classes=4.
#define B_ 8
#define C_ 5
#define H_ 768
#define W_ 768
#define HW_ (H_*W_)
#define HWq (HW_/4)            // 147456 float4 per plane
#define NPIX (B_*HW_)          // 4,718,592
#define TB 8
#define INVAL 0xFFFFFFFFu
#define LN2F 0.69314718056f
#define BIASF 16.2f
#define TILE 32
#define TPR 24                 // tiles per row (W/32)
#define TPC 24                 // tile rows (H/32)
#define NTILES (B_*TPR*TPC)    // 4608
#define NPT 128                // border nodes per tile (4*32)
#define NNODES (NTILES*NPT)    // 589,824
#define NCOPY 16               // histogram replicas (LDS)
#define EPI (23*24*2)          // edges per image: 552 vertical + 552 horizontal
#define NEDGE (B_*EPI)         // 8832
#define REPS 8                 // global sp replicas
#define REPC 64                // global ctrl-counter replicas (16 u32 = 64B stride each)
// zero region (u32 words): ctrl(16) | crep(REPC*16=1024) | spu(REPS*160 u64 = 2560) | flags(8832)
#define ZWORDS (16 + REPC*16 + REPS*160*2 + NEDGE)   // 12432
#define ZBLK 49

typedef unsigned long long ull;

// ---------------- compact node union-find (lock-free, agent scope, coherent-point) ---------
static __device__ __forceinline__ unsigned pload(const unsigned* P, unsigned i) {
  return __hip_atomic_load(&P[i], __ATOMIC_RELAXED, __HIP_MEMORY_SCOPE_AGENT);
}
static __device__ unsigned findRootG(unsigned* P, unsigned i) {
  unsigned p = pload(P, i);
  if (p == i) return i;
  unsigned gp = pload(P, p);
  while (p != gp) {
    __hip_atomic_store(&P[i], gp, __ATOMIC_RELAXED, __HIP_MEMORY_SCOPE_AGENT);  // path halving
    i = p; p = gp; gp = pload(P, p);
  }
  return p;
}
static __device__ bool uniteG(unsigned* P, unsigned a, unsigned b) {
  a = findRootG(P, a);
  b = findRootG(P, b);
  while (a != b) {
    if (a < b) { unsigned t = a; a = b; b = t; }
    unsigned old = atomicCAS(&P[a], a, b);
    if (old == a) return true;     // one real merge
    a = findRootG(P, old);
    b = findRootG(P, b);
  }
  return false;
}
// ---------------- LDS union-find with high-16-bit payload (workgroup scope) ----------------
static __device__ __forceinline__ unsigned ploadL(const unsigned* P, unsigned i) {
  return __hip_atomic_load(&P[i], __ATOMIC_RELAXED, __HIP_MEMORY_SCOPE_WORKGROUP);
}
static __device__ unsigned findRootL(const unsigned* P, unsigned i) {
  unsigned p = ploadL(P, i) & 0xFFFFu;
  while (p != i) { i = p; p = ploadL(P, i) & 0xFFFFu; }
  return i;
}
static __device__ void uniteL(unsigned* P, unsigned a, unsigned b) {
  a = findRootL(P, a);
  b = findRootL(P, b);
  while (a != b) {
    if (a < b) { unsigned t = a; a = b; b = t; }
    unsigned old = atomicCAS(&P[a], 0xFFFF0000u | a, 0xFFFF0000u | b);
    if (old == (0xFFFF0000u | a)) return;
    a = findRootL(P, old & 0xFFFFu);
    b = findRootL(P, b);
  }
}

// ---------------- k0: zero control region (ctrl | crep | spu | flags) ----------------------
__global__ __launch_bounds__(256) void k_zero(unsigned* __restrict__ z) {
  unsigned idx = blockIdx.x * 256u + threadIdx.x;
  if (idx < ZWORDS) z[idx] = 0u;
}

// ---------------- k_fused: stats + tile-CCL + seam-arbitration + last-block finalize -------
// hist word: [63:57] cnt | [56:38] sum pred*2^12 | [37:20] sum (logit+16.2)*2^6 | [16:0] sum mag*2^6
// Global sp reduction: per-block partial s is an exact multiple of 2^-12 -> llrint(s*4096)
// accumulated with hardware u64 atomicAdd into REPS replicas (bit-exact, order-independent).
#define SH_CNT(t,c)   shist[((t)*C_+(c))*4 + 0]
#define SH_PRED(t,c)  shist[((t)*C_+(c))*4 + 1]
#define SH_LRAW(t,c)  shist[((t)*C_+(c))*4 + 2]
#define SH_MAG(t,c)   shist[((t)*C_+(c))*4 + 3]
__global__ __launch_bounds__(256, 8) void k_fused(
    const float* __restrict__ pred, const int* __restrict__ tgt,
    const int* __restrict__ ntcp,
    unsigned* __restrict__ border32, unsigned* __restrict__ P2,
    unsigned* __restrict__ flags, unsigned* __restrict__ ctrl,
    unsigned* __restrict__ crep, ull* __restrict__ spu,
    float* __restrict__ out)
{
  __shared__ ull h[NCOPY][41];               // 5,248 B
  __shared__ unsigned lab[TILE*TILE];        // 4 KB (payload in high 16 bits)
  __shared__ unsigned lclsw[TILE*TILE/4];    // 1 KB
  __shared__ unsigned s_rt[4], s_sm[4];
  __shared__ unsigned s_bord[NPT];
  __shared__ int s_win[4];
  __shared__ int s_last;
  // finalize-phase arrays (used only by the last block)
  __shared__ double shist[160];
  __shared__ double s_col[C_][3];
  __shared__ unsigned s_cnti[TB*C_];
  __shared__ unsigned s_ctot[C_];
  __shared__ unsigned s_nc[4], s_smg[4];
  __shared__ float s_ph[C_];
  __shared__ double s_term[TB];
  __shared__ int s_NT;
  __shared__ int s_nun;
  unsigned char* lcls = (unsigned char*)lclsw;

  for (int i = threadIdx.x; i < NCOPY*41; i += 256) (&h[0][0])[i] = 0ull;
  if (threadIdx.x < 4) { s_rt[threadIdx.x] = 0u; s_sm[threadIdx.x] = 0u; }
  if (threadIdx.x < NPT) {   // agent-scope init (coherent point, readable cross-XCD)
    unsigned n = (unsigned)blockIdx.x * NPT + threadIdx.x;
    __hip_atomic_store(&P2[n], n, __ATOMIC_RELAXED, __HIP_MEMORY_SCOPE_AGENT);
  }
  __syncthreads();

  const int cp = threadIdx.x & (NCOPY - 1);
  int blk = blockIdx.x;
  int b = blk / (TPR*TPC);
  int rem = blk - b * (TPR*TPC);
  int trow = rem / TPR;
  int tcol = rem - trow * TPR;
  int ty0 = trow * TILE;
  int tx0 = tcol * TILE;

  // ---- load + stats phase: one quad per thread ----
  unsigned pk = 0u;
  {
    const int baseq = ty0 * (W_/4) + (tx0 >> 2);
    const int qrow = threadIdx.x >> 3, qcol = threadIdx.x & 7;
    const int o = qrow * (W_/4) + qcol;
    const float4* pp = (const float4*)pred + (size_t)b * (C_*HWq) + baseq + o;
    float4 a0 = pp[0];
    float4 a1 = pp[HWq];
    float4 a2 = pp[2*HWq];
    float4 a3 = pp[3*HWq];
    float4 a4 = pp[4*HWq];
    int4 t4 = ((const int4*)tgt)[(size_t)b * HWq + baseq + o];
#pragma unroll
    for (int j = 0; j < 4; ++j) {
      float v0 = ((const float*)&a0)[j];
      float v1 = ((const float*)&a1)[j];
      float v2 = ((const float*)&a2)[j];
      float v3 = ((const float*)&a3)[j];
      float v4 = ((const float*)&a4)[j];
      int tt = ((const int*)&t4)[j];
      float best = v0; int bc = 0;
      if (v1 > best) { best = v1; bc = 1; }
      if (v2 > best) { best = v2; bc = 2; }
      if (v3 > best) { best = v3; bc = 3; }
      if (v4 > best) { best = v4; bc = 4; }
      unsigned tu = (unsigned)tt; if (tu >= TB) tu = TB - 1;
      ull w;
      if (bc) {
        float pc = fminf(fmaxf(best, 1e-7f), 1.0f - 1e-7f);
        float l2p = __log2f(pc);
        float l2m = __log2f(1.0f - pc);
        float logit = (l2p - l2m) * LN2F;
        float mag   = -l2m * LN2F;
        w = (1ull << 57)
          | ((ull)__float2uint_rn(best * 4096.0f) << 38)
          | ((ull)__float2uint_rn((logit + BIASF) * 64.0f) << 20)
          | (ull)__float2uint_rn(mag * 64.0f);
      } else {
        w = 1ull << 57;
      }
      atomicAdd(&h[cp][(int)tu * C_ + bc], w);
      pk |= ((unsigned)bc) << (8 * j);
    }
    lclsw[threadIdx.x] = pk;
  }
  __syncthreads();

  // ---- CCL phase: thread owns its own 4-px quad ----
  const int r = threadIdx.x >> 3, sub = threadIdx.x & 7;
  const int seg = r * TILE + sub * 4;
  unsigned Dw = (r < TILE-1) ? lclsw[threadIdx.x + 8] : 0u;
  unsigned rb = (sub < 7) ? (lclsw[threadIdx.x + 1] & 255u) : 0u;
  {
    uint4 lw;
    unsigned* lp = (unsigned*)&lw;
#pragma unroll
    for (int k = 0; k < 4; ++k) {
      int li = seg + k;
      unsigned c = (pk >> (8 * k)) & 255u;
      lp[k] = c ? (0xFFFF0000u | (unsigned)li) : INVAL;
    }
    *(uint4*)&lab[seg] = lw;
  }
  __syncthreads();

#pragma unroll
  for (int j = 0; j < 4; ++j) {
    unsigned c = (pk >> (8 * j)) & 255u;
    if (!c) continue;
    int li = seg + j;
    unsigned cr = (j < 3) ? ((pk >> (8 * (j + 1))) & 255u) : rb;
    if (cr == c) uniteL(lab, li, li + 1);
    if (((Dw >> (8 * j)) & 255u) == c) uniteL(lab, li, li + TILE);
  }
  __syncthreads();

  {
    uint4 lw = *(const uint4*)&lab[seg];
    const unsigned* lp = (const unsigned*)&lw;
#pragma unroll
    for (int k = 0; k < 4; ++k) {
      int li = seg + k;
      unsigned c = (pk >> (8 * k)) & 255u;
      if (c && (lp[k] & 0xFFFFu) == (unsigned)li) atomicAdd(&s_rt[c - 1], 1u);
    }
  }
  // border representative election (low 16 bits of lab[root] invariant under atomicMin)
  unsigned bc_c = 0, bc_rt = 0;
  if (threadIdx.x < NPT) {
    int bp = threadIdx.x;
    int tx, ty;
    if (bp < 32)       { ty = 0;       tx = bp; }
    else if (bp < 64)  { ty = TILE-1;  tx = bp - 32; }
    else if (bp < 96)  { tx = 0;       ty = bp - 64; }
    else               { tx = TILE-1;  ty = bp - 96; }
    int li = ty * TILE + tx;
    bc_c = lcls[li];
    if (bc_c) {
      bc_rt = findRootL(lab, (unsigned)li);
      atomicMin(&lab[bc_rt], ((unsigned)threadIdx.x << 16) | bc_rt);
    }
  }
  __syncthreads();
  if (threadIdx.x < NPT) {
    unsigned sub2 = bc_c ? (lab[bc_rt] >> 16) : 0u;
    s_bord[threadIdx.x] = (bc_c << 8) | sub2;
  }
  __syncthreads();
  // publish border via agent-scope atomic stores (coherent point)
  if (threadIdx.x < NPT/2) {
    unsigned wv = s_bord[2*threadIdx.x] | (s_bord[2*threadIdx.x + 1] << 16);
    __hip_atomic_store(&border32[blk * (NPT/2) + threadIdx.x], wv,
                       __ATOMIC_RELAXED, __HIP_MEMORY_SCOPE_AGENT);
  }
  __syncthreads();   // vmcnt drain: publish + P2 init acked before flag arbitration

  // ---- seam arbitration: second arriver on each edge owns it ----
  if (threadIdx.x < 4) {
    s_win[threadIdx.x] = 0;
    int valid = 0; unsigned eid = 0;
    if (threadIdx.x == 0) { valid = (trow > 0);       eid = b*EPI + (trow-1)*24 + tcol; }
    if (threadIdx.x == 1) { valid = (trow < TPC-1);   eid = b*EPI + trow*24 + tcol; }
    if (threadIdx.x == 2) { valid = (tcol > 0);       eid = b*EPI + 552 + trow*23 + (tcol-1); }
    if (threadIdx.x == 3) { valid = (tcol < TPR-1);   eid = b*EPI + 552 + trow*23 + tcol; }
    if (valid) {
      unsigned old = __hip_atomic_fetch_add(&flags[eid], 1u,
                       __ATOMIC_RELAXED, __HIP_MEMORY_SCOPE_AGENT);
      if (old == 1u) s_win[threadIdx.x] = 1;
    }
  }
  __syncthreads();
  {
    int d = threadIdx.x >> 5;
    int k = threadIdx.x & 31;
    if (d < 4 && s_win[d]) {
      int tA, tB, pA, pB;
      if (d == 0)      { tA = blk - TPR; tB = blk;       pA = 32 + k; pB = 0 + k; }
      else if (d == 1) { tA = blk;       tB = blk + TPR; pA = 32 + k; pB = 0 + k; }
      else if (d == 2) { tA = blk - 1;   tB = blk;       pA = 96 + k; pB = 64 + k; }
      else             { tA = blk;       tB = blk + 1;   pA = 96 + k; pB = 64 + k; }
      unsigned wA = __hip_atomic_load(&border32[tA * (NPT/2) + (pA >> 1)],
                      __ATOMIC_RELAXED, __HIP_MEMORY_SCOPE_AGENT);
      unsigned wB = __hip_atomic_load(&border32[tB * (NPT/2) + (pB >> 1)],
                      __ATOMIC_RELAXED, __HIP_MEMORY_SCOPE_AGENT);
      unsigned eA = (pA & 1) ? (wA >> 16) : (wA & 0xFFFFu);
      unsigned eB = (pB & 1) ? (wB >> 16) : (wB & 0xFFFFu);
      unsigned ca = eA >> 8, cb = eB >> 8;
      if (ca && ca == cb) {
        if (uniteG(P2, (unsigned)tA * NPT + (eA & 255u),
                       (unsigned)tB * NPT + (eB & 255u)))
          atomicAdd(&s_sm[ca - 1], 1u);
      }
    }
  }
  // ---- histogram fold -> fixed-point u64 hardware atomics (replicated) ----
  if (threadIdx.x < 160) {
    int slot = threadIdx.x >> 2, comp = threadIdx.x & 3;
    double s = 0.0;
#pragma unroll
    for (int cc = 0; cc < NCOPY; ++cc) {
      ull w = h[cc][slot];
      if (comp == 0)      s += (double)(w >> 57);
      else if (comp == 1) s += (double)((w >> 38) & 0x7FFFFull) * (1.0/4096.0);
      else if (comp == 2) s += (double)((w >> 20) & 0x3FFFFull) * (1.0/64.0);
      else                s += (double)(w & 0x1FFFFull) * (1.0/64.0);
    }
    if (s != 0.0) {
      ull iv = (ull)llrint(s * 4096.0);   // exact: s is a multiple of 2^-12
      atomicAdd(&spu[(blk & (REPS-1)) * 160 + threadIdx.x], iv);
    }
  }
  __syncthreads();
  if (threadIdx.x < 4) {
    unsigned repbase = (blk & (REPC-1)) * 16;
    if (s_rt[threadIdx.x])
      __hip_atomic_fetch_add(&crep[repbase + threadIdx.x], s_rt[threadIdx.x],
                             __ATOMIC_RELAXED, __HIP_MEMORY_SCOPE_AGENT);
    if (s_sm[threadIdx.x])
      __hip_atomic_fetch_add(&crep[repbase + 4 + threadIdx.x], s_sm[threadIdx.x],
                             __ATOMIC_RELAXED, __HIP_MEMORY_SCOPE_AGENT);
  }
  __syncthreads();   // all of this block's global atomics issued+acked
  if (threadIdx.x == 0) {
    unsigned old = __hip_atomic_fetch_add(&ctrl[8], 1u,
                     __ATOMIC_RELAXED, __HIP_MEMORY_SCOPE_AGENT);
    s_last = (old == (unsigned)(NTILES - 1));
  }
  __syncthreads();
  if (!s_last) return;

  // ================= finalize (exactly one block reaches here) =================
  if (threadIdx.x < 160) {
    ull acc = 0;
#pragma unroll
    for (int rp = 0; rp < REPS; ++rp)
      acc += __hip_atomic_load(&spu[rp * 160 + threadIdx.x],
               __ATOMIC_RELAXED, __HIP_MEMORY_SCOPE_AGENT);
    shist[threadIdx.x] = (double)acc * (1.0 / 4096.0);   // exact (power-of-2 scale)
  }
  if (threadIdx.x < 8) {
    unsigned acc = 0;
    for (int rp = 0; rp < REPC; ++rp)
      acc += __hip_atomic_load(&crep[rp * 16 + threadIdx.x],
               __ATOMIC_RELAXED, __HIP_MEMORY_SCOPE_AGENT);
    if (threadIdx.x < 4) s_nc[threadIdx.x] = acc;
    else                 s_smg[threadIdx.x - 4] = acc;
  }
  if (threadIdx.x < TB) s_term[threadIdx.x] = 0.0;
  if (threadIdx.x == 0) {
    int NT = ntcp[0];
    if (NT < 1) NT = 1;
    if (NT > TB) NT = TB;
    s_NT = NT;
  }
  __syncthreads();

  if (threadIdx.x < TB * C_) s_cnti[threadIdx.x] = (unsigned)llrint(shist[threadIdx.x * 4]);
  __syncthreads();

  if (threadIdx.x < C_) {
    int c = threadIdx.x;
    double sc = 0.0, sp2 = 0.0, sl = 0.0;
    unsigned ct = 0;
#pragma unroll
    for (int t = 0; t < TB; ++t) {
      sc += SH_CNT(t, c);
      sp2 += SH_PRED(t, c);
      sl += -SH_MAG(t, c);
      ct += s_cnti[t * C_ + c];
    }
    s_col[c][0] = sc; s_col[c][1] = sp2; s_col[c][2] = sl;
    s_ctot[c] = ct;
  }
  __syncthreads();

  // ph_tab: exact f32 replay incl. int32 wrap of n_comp*last_i
  if (threadIdx.x == 0) {
#pragma unroll
    for (int cc = 0; cc < C_; ++cc) {
      float ph = 0.0f;
      int li = 1;
#pragma unroll
      for (int v = 1; v < C_; ++v) {
        unsigned ncv = s_nc[v - 1] - s_smg[v - 1];
        if (s_ctot[v] > 0) {
          int prod = (int)(ncv * (unsigned)li);
          float sv = (float)prod;
          float inc = ((cc == v) ? 1.0f : 0.0f) + sv;
          ph = ph + inc;
          li = li + (int)ncv + ((s_ctot[v] < (unsigned)NPIX) ? 1 : 0);
        }
      }
      s_ph[cc] = ph;
    }
  }
  __syncthreads();

  const float EPSF = 1e-7f;
  const double L1 = (double)logf(1.0f - EPSF);
  const double M1 = (double)log1pf(-(1.0f - EPSF));
  const double L0 = (double)logf(EPSF);
  const double M0 = (double)log1pf(-EPSF);
  const double N = (double)NPIX;
  const double BIASD = (double)BIASF;
  const int NT = s_NT;

  if (threadIdx.x == 0) {
    double nt0 = 0;
#pragma unroll
    for (int c = 0; c < C_; ++c) nt0 += SH_CNT(0, c);
    double np1 = (double)s_ctot[0];
    double n11 = SH_CNT(0, 0);
    s_term[0] = -(n11*L1 + (nt0 - n11)*L0 + (np1 - n11)*M1 + (N - nt0 - np1 + n11)*M0) / N
                + 1.0 - (2.0*n11 + 1.0) / (np1 + nt0 + 1.0);
    int nun = 0;
    for (int t = 0; t < NT; ++t) {
      long long s = 0;
#pragma unroll
      for (int c = 0; c < C_; ++c) s += (long long)s_cnti[t * C_ + c];
      if (s) nun++;
    }
    s_nun = nun;
  } else if (threadIdx.x < (unsigned)NT) {
    int t = threadIdx.x;
    long long ntti = 0;
#pragma unroll
    for (int c = 0; c < C_; ++c) ntti += (long long)s_cnti[t * C_ + c];
    if (ntti != 0) {
      double ntt = 0;
#pragma unroll
      for (int c = 0; c < C_; ++c) ntt += SH_CNT(t, c);
      float pht[C_] = {s_ph[0], s_ph[1], s_ph[2], s_ph[3], s_ph[4]};
      int idx[C_] = {0, 1, 2, 3, 4};
#pragma unroll
      for (int i = 1; i < C_; ++i)
        for (int j = i; j > 0 && pht[idx[j]] < pht[idx[j-1]]; --j) {
          int tmp = idx[j]; idx[j] = idx[j-1]; idx[j-1] = tmp;
        }
      long long k = (ntti - 1) / 2;
      float med = pht[idx[C_ - 1]];
      long long cum = 0;
#pragma unroll
      for (int i = 0; i < C_; ++i) {
        cum += (long long)s_cnti[t * C_ + idx[i]];
        if (cum > k) { med = pht[idx[i]]; break; }
      }
      double A = 0, Bt = 0, inter = 0, sum_p = 0, ex = 0, nfg_t = 0, nfg_all = 0;
#pragma unroll
      for (int c = 1; c < C_; ++c) {
        double cnt_tc = SH_CNT(t, c);
        double mag_tc = SH_MAG(t, c);
        double spred_tc = SH_PRED(t, c);
        if (pht[c] == med) {
          double logit = SH_LRAW(t, c) - BIASD * cnt_tc;
          A += logit - mag_tc;                 // logpc = logit + log1m
          inter += spred_tc;
          nfg_t += cnt_tc;
          nfg_all += s_col[c][0];
          sum_p += s_col[c][1];
          Bt += s_col[c][2] - (-mag_tc);       // sum over t2 != t of log1m
        } else {
          ex += spred_tc;
        }
      }
      double bce  = -(A + Bt + (ntt - nfg_t)*L0 + (N - ntt - (nfg_all - nfg_t))*M0) / N;
      double dice = 1.0 - (2.0*inter + 1.0) / (sum_p + ntt + 1.0);
      s_term[t] = bce + dice + ex / ntt;
    }
  }
  __syncthreads();
  if (threadIdx.x == 0) {
    double res = 0.0;
#pragma unroll
    for (int t = 0; t < TB; ++t) res += s_term[t];
    out[0] = (float)(res / (double)(2 * s_nun + 1));
  }
}

extern "C" void kernel_launch(void* const* d_in, const int* in_sizes, int n_in,
                              void* d_out, int out_size, void* d_ws, size_t ws_size,
                              hipStream_t stream) {
  const float* pred = (const float*)d_in[0];
  const int* tgt = (const int*)d_in[1];
  const int* ntc = (const int*)d_in[2];
  float* out = (float*)d_out;
  char* ws = (char*)d_ws;
  // ws layout: ctrl(16 u32) | crep(1024 u32) | spu(1280 u64) | flags(8832 u32) | P2 | border32
  size_t off = 0;
  unsigned* ctrl = (unsigned*)(ws + off);        off += 16 * 4;                     // 64
  unsigned* crep = (unsigned*)(ws + off);        off += (size_t)REPC * 16 * 4;      // 4,096
  ull* spu = (ull*)(ws + off);                   off += (size_t)REPS * 160 * 8;     // 10,240
  unsigned* flags = (unsigned*)(ws + off);       off += (size_t)NEDGE * 4;          // 35,328
  unsigned* P2 = (unsigned*)(ws + off);          off += (size_t)NNODES * 4;         // 2,359,296
  unsigned* border32 = (unsigned*)(ws + off);    off += (size_t)NTILES * (NPT/2) * 4; // 1,179,648

  hipLaunchKernelGGL(k_zero, dim3(ZBLK), dim3(256), 0, stream, (unsigned*)ws);
  hipLaunchKernelGGL(k_fused, dim3(NTILES), dim3(256), 0, stream,
                     pred, tgt, ntc, border32, P2, flags, ctrl, crep, spu, out);
}